// Round 3
// baseline (482.272 us; speedup 1.0000x reference)
//
#include <hip/hip_runtime.h>
#include <hip/hip_bf16.h>

#define NN 100000
#define EE 1000000
#define FIN 15
#define HH 64
#define EMBD 128
#define RR 13
#define NBASE 4
#define NP 391          // ceil(NN/256) scan blocks
#define CAP 1700128     // EE + 7*NN + slack (padded edge capacity, mult of 16)
#define SENT (15 << 17) // sentinel packed word: src=0, rel=15 (zero coeffs)

typedef __hip_bfloat16 bf16;
typedef __attribute__((ext_vector_type(8))) short short8;   // MFMA A/B frag (8 bf16)
typedef __attribute__((ext_vector_type(4))) float f32x4;    // MFMA C/D frag

__device__ __forceinline__ float b2f(bf16 x) { return __bfloat162float(x); }
__device__ __forceinline__ float bcast(float v, int l) {
    return __uint_as_float(__builtin_amdgcn_readlane(__float_as_uint(v), l));
}
__device__ __forceinline__ int bcasti(int v, int l) {
    return (int)__builtin_amdgcn_readlane((unsigned)v, l);
}
__device__ __forceinline__ unsigned short f2bu(float f) {
    bf16 t = __float2bfloat16(f);
    return *reinterpret_cast<unsigned short*>(&t);
}
__device__ __forceinline__ float bu2f(unsigned u) {
    return __uint_as_float(u << 16);
}

// ---------- dtype auto-detect ----------
__global__ void k_detect(const void* __restrict__ win, int* __restrict__ flag) {
    int tid = threadIdx.x;
    const bf16* p = (const bf16*)win;
    int cnt = 0;
    for (int i = tid; i < FIN * HH; i += 64) {
        float v = b2f(p[i]);
        if (!(fabsf(v) < 0.3f)) cnt++;
    }
#pragma unroll
    for (int off = 32; off > 0; off >>= 1) cnt += __shfl_down(cnt, off, 64);
    if (tid == 0) *flag = (cnt > 40) ? 1 : 0;
}

// ---------- fused convert ----------
struct ConvTab {
    const void* in[17];
    int n[17];
    int cum[18];
};

__global__ void k_convert_all(ConvTab tab, float* __restrict__ base,
                              const int* __restrict__ flag) {
    int g = blockIdx.x * 256 + threadIdx.x;
    if (g >= tab.cum[17]) return;
    int t = 0;
#pragma unroll
    for (int i = 0; i < 17; ++i) if (g >= tab.cum[i + 1]) t = i + 1;
    int local = g - tab.cum[t];
    if (local >= tab.n[t]) return;
    float v;
    if (*flag) v = ((const float*)tab.in[t])[local];
    else       v = b2f(((const bf16*)tab.in[t])[local]);
    base[g] = v;
}

// ---------- init: zero count + rcnt, sentinel-fill packed (fused) ----------
__global__ void k_init(int* __restrict__ count, int* __restrict__ rcnt,
                       int* __restrict__ packed) {
    int i = blockIdx.x * 256 + threadIdx.x;
    if (i < NN) count[i] = 0;
    else if (i < 2 * NN) rcnt[i - NN] = 0;
    else if (i < 2 * NN + CAP) packed[i - 2 * NN] = SENT;
}

// count-only histogram (rank re-derived in scatter via rcnt atomics)
__global__ void k_hist(const int* __restrict__ tgt, int* __restrict__ count) {
    int e = blockIdx.x * 256 + threadIdx.x;
    if (e >= EE) return;
    atomicAdd(&count[tgt[e]], 1);
}

// exclusive scan over PADDED counts ((c+7)&~7)
__global__ void k_scan1(const int* __restrict__ count, int* __restrict__ scanned,
                        int* __restrict__ partials) {
    __shared__ int buf[256];
    int tid = threadIdx.x;
    int i = blockIdx.x * 256 + tid;
    int v = (i < NN) ? ((count[i] + 7) & ~7) : 0;
    buf[tid] = v;
    __syncthreads();
    for (int off = 1; off < 256; off <<= 1) {
        int t = (tid >= off) ? buf[tid - off] : 0;
        __syncthreads();
        buf[tid] += t;
        __syncthreads();
    }
    if (i < NN) scanned[i] = buf[tid] - v;
    if (tid == 255) partials[blockIdx.x] = buf[255];
}

__global__ void k_scan2(int* __restrict__ partials) {
    __shared__ int buf[512];
    int tid = threadIdx.x;
    int v = (tid < NP) ? partials[tid] : 0;
    buf[tid] = v;
    __syncthreads();
    for (int off = 1; off < 512; off <<= 1) {
        int t = (tid >= off) ? buf[tid - off] : 0;
        __syncthreads();
        buf[tid] += t;
        __syncthreads();
    }
    if (tid < NP) partials[tid] = buf[tid] - v;
}

// packed word: src(17) | etype(4)<<17; sentinel slots stay prefilled.
// rank derived here via rcnt atomics (rank array eliminated).
__global__ void k_scatter(const int* __restrict__ src, const int* __restrict__ tgt,
                          const int* __restrict__ et,
                          const int* __restrict__ scanned, const int* __restrict__ partials,
                          int* __restrict__ rcnt, int* __restrict__ packed) {
    int e = blockIdx.x * 256 + threadIdx.x;
    if (e >= EE) return;
    int t = tgt[e];
    int r = atomicAdd(&rcnt[t], 1);
    int pos = scanned[t] + partials[t >> 8] + r;
    packed[pos] = src[e] | (et[e] << 17);
}

// ---------- fused weight prep: coeff tables + WcatT + WnpT hi/lo ----------
// idx [0,64): 16-row coeff tables (rows 13..15 = 0 so sentinels contribute 0)
// idx [64, 64+20480): WcatT[n][k] bf16 for both layers
//   k 0..255: bases[k>>6][k&63][n]; k 256..319: Wself[k-256][n]
// idx [64+20480, 64+20480+8192): WnpT hi/lo split (col-major [128][64]);
//   hi+lo recovers fp32 weight accuracy through two bf16 MFMAs.
#define PREP_WCAT (HH * 320)
#define PREP_WT   (EMBD * HH)
__global__ void k_prep(const float* __restrict__ c0, const float* __restrict__ c1,
                       float* __restrict__ o0, float* __restrict__ o1,
                       const float* __restrict__ bases0, const float* __restrict__ Wself0,
                       const float* __restrict__ bases1, const float* __restrict__ Wself1,
                       unsigned short* __restrict__ W0, unsigned short* __restrict__ W1,
                       const float* __restrict__ Wnp, unsigned short* __restrict__ WT) {
    int idx = blockIdx.x * 256 + threadIdx.x;
    if (idx < 64) {
        int r = idx >> 2, b = idx & 3;
        o0[idx] = (r < RR) ? c0[r * NBASE + b] : 0.f;
        o1[idx] = (r < RR) ? c1[r * NBASE + b] : 0.f;
        return;
    }
    idx -= 64;
    if (idx < PREP_WCAT) {
        int n = idx / 320, k = idx - n * 320;
        int b = k >> 6, kk = k & 63;
        float v0 = (b < 4) ? bases0[b * 4096 + kk * 64 + n] : Wself0[kk * 64 + n];
        float v1 = (b < 4) ? bases1[b * 4096 + kk * 64 + n] : Wself1[kk * 64 + n];
        W0[idx] = f2bu(v0);
        W1[idx] = f2bu(v1);
        return;
    }
    idx -= PREP_WCAT;
    if (idx < PREP_WT) {
        int c = idx >> 6, k = idx & 63;
        float w = Wnp[k * EMBD + c];
        unsigned short hi = f2bu(w);
        WT[idx] = hi;
        WT[PREP_WT + idx] = f2bu(w - bu2f(hi));
    }
}

// ---------- pipeline (bf16 node state) ----------

__global__ void k_input_proj(const float* __restrict__ nf, const float* __restrict__ Win,
                             const float* __restrict__ bin, unsigned short* __restrict__ h) {
    __shared__ float w[FIN * HH];
    __shared__ float bb[HH];
    int tid = threadIdx.x;
    for (int i = tid; i < FIN * HH; i += 256) w[i] = Win[i];
    if (tid < HH) bb[tid] = bin[tid];
    __syncthreads();
    int idx = blockIdx.x * 256 + tid;
    if (idx >= NN * HH) return;
    int n = idx >> 6, j = idx & 63;
    float acc = bb[j];
    const float* row = nf + n * FIN;
#pragma unroll
    for (int k = 0; k < FIN; ++k) acc = fmaf(row[k], w[k * HH + j], acc);
    h[idx] = f2bu(acc);
}

// --- k_layer phase-1 inner bodies: edge groups, NO masking (sentinel-padded) ---
// hin gathers use nontemporal loads: the random stream has no reuse within a CU,
// so keep it from evicting packed/metadata/Wc lines out of L1.
__device__ __forceinline__ void edge_group16(const unsigned short* __restrict__ hin,
                                             const float* __restrict__ cc,
                                             int lane, int pk, int j, float S[4]) {
    float hv[16];
    int rr[16];
#pragma unroll
    for (int k = 0; k < 16; ++k) {
        int v = bcasti(pk, j + k);          // scalar
        rr[k] = (v >> 17) & 0xF;
        unsigned short us = __builtin_nontemporal_load(hin + (v & 0x1FFFF) * HH + lane);
        hv[k] = bu2f((unsigned)us);         // 16 coalesced 128B gathers in flight
    }
#pragma unroll
    for (int hh = 0; hh < 2; ++hh) {
        float4 cv[8];
#pragma unroll
        for (int k = 0; k < 8; ++k)
            cv[k] = *(const float4*)(cc + rr[hh * 8 + k] * 4);   // uniform -> s_load
#pragma unroll
        for (int k = 0; k < 8; ++k) {
            float hk = hv[hh * 8 + k];
            S[0] = fmaf(cv[k].x, hk, S[0]);
            S[1] = fmaf(cv[k].y, hk, S[1]);
            S[2] = fmaf(cv[k].z, hk, S[2]);
            S[3] = fmaf(cv[k].w, hk, S[3]);
        }
    }
}

__device__ __forceinline__ void edge_group8(const unsigned short* __restrict__ hin,
                                            const float* __restrict__ cc,
                                            int lane, int pk, int j, float S[4]) {
    float hv[8];
    int rr[8];
#pragma unroll
    for (int k = 0; k < 8; ++k) {
        int v = bcasti(pk, j + k);
        rr[k] = (v >> 17) & 0xF;
        unsigned short us = __builtin_nontemporal_load(hin + (v & 0x1FFFF) * HH + lane);
        hv[k] = bu2f((unsigned)us);
    }
    float4 cv[8];
#pragma unroll
    for (int k = 0; k < 8; ++k) cv[k] = *(const float4*)(cc + rr[k] * 4);
#pragma unroll
    for (int k = 0; k < 8; ++k) {
        float hk = hv[k];
        S[0] = fmaf(cv[k].x, hk, S[0]);
        S[1] = fmaf(cv[k].y, hk, S[1]);
        S[2] = fmaf(cv[k].z, hk, S[2]);
        S[3] = fmaf(cv[k].w, hk, S[3]);
    }
}

__device__ __forceinline__ void gather_node(const unsigned short* __restrict__ hin,
                                            const int* __restrict__ packed,
                                            const float* __restrict__ cc,
                                            int lane, int pk, int s0, int cntp,
                                            float S[4]) {
    int lim = min(64, cntp);                // cntp is a multiple of 8
    int j = 0;
    for (; j + 16 <= lim; j += 16) edge_group16(hin, cc, lane, pk, j, S);
    if (j < lim) edge_group8(hin, cc, lane, pk, j, S);
    for (int base = 64; base < cntp; base += 64) {   // rare overflow (deg > 64)
        int pkx = packed[s0 + base + lane];
        int lim2 = min(64, cntp - base);
        int j2 = 0;
        for (; j2 + 16 <= lim2; j2 += 16) edge_group16(hin, cc, lane, pkx, j2, S);
        if (j2 < lim2) edge_group8(hin, cc, lane, pkx, j2, S);
    }
}

// Fused RGCN layer, 16 nodes/block:
//  phase 1 (register gather, NO atomics, NO masks — sentinel-padded edge lists):
//     metadata int4-prefetched, packed words for all 4 nodes prefetched up front,
//     16-deep gather bursts. NOTE (r2 post-mortem): per-CU miss-throughput bound
//     (MSHR x latency); depth>8 and occupancy changes measured neutral.
//  phase 2 (MFMA, layout verified in r7): out = relu([S|h] @ WcatT^T + bself)
__global__ void __launch_bounds__(256, 6)
k_layer(const unsigned short* __restrict__ hin, const int* __restrict__ packed,
        const int* __restrict__ count, const int* __restrict__ scanned,
        const int* __restrict__ partials, const float* __restrict__ cc,
        const unsigned short* __restrict__ Wc, const float* __restrict__ bself,
        unsigned short* __restrict__ hout) {
    __shared__ __align__(16) unsigned short Sb[16 * 264];   // row stride 264 (16B-aligned)
    int tid = threadIdx.x;
    int lane = tid & 63;
    int wv = tid >> 6;
    int t0 = blockIdx.x * 16;
    int nb = t0 + wv * 4;

    // metadata for all 4 nodes in 2 int4 loads (+1 scalar: whole block shares t0>>8)
    int4 c4  = *(const int4*)(count + nb);
    int4 sc4 = *(const int4*)(scanned + nb);
    int pb = partials[t0 >> 8];
    int s00 = sc4.x + pb, s01 = sc4.y + pb, s02 = sc4.z + pb, s03 = sc4.w + pb;
    int cp0 = (c4.x + 7) & ~7, cp1 = (c4.y + 7) & ~7;
    int cp2 = (c4.z + 7) & ~7, cp3 = (c4.w + 7) & ~7;

    // prefetch packed words for all 4 nodes (4 loads in flight before any consume)
    int pk0 = packed[s00 + lane];
    int pk1 = packed[s01 + lane];
    int pk2 = packed[s02 + lane];
    int pk3 = packed[s03 + lane];

    float S0[4] = {0, 0, 0, 0}, S1[4] = {0, 0, 0, 0};
    float S2[4] = {0, 0, 0, 0}, S3[4] = {0, 0, 0, 0};
    gather_node(hin, packed, cc, lane, pk0, s00, cp0, S0);
    gather_node(hin, packed, cc, lane, pk1, s01, cp1, S1);
    gather_node(hin, packed, cc, lane, pk2, s02, cp2, S2);
    gather_node(hin, packed, cc, lane, pk3, s03, cp3, S3);

    // write S to LDS bf16: row = local node, k = b*64+lane  (stride-1 across lanes)
#pragma unroll
    for (int b = 0; b < NBASE; ++b) {
        Sb[(wv * 4 + 0) * 264 + b * 64 + lane] = f2bu(S0[b]);
        Sb[(wv * 4 + 1) * 264 + b * 64 + lane] = f2bu(S1[b]);
        Sb[(wv * 4 + 2) * 264 + b * 64 + lane] = f2bu(S2[b]);
        Sb[(wv * 4 + 3) * 264 + b * 64 + lane] = f2bu(S3[b]);
    }
    __syncthreads();

    // phase 2: MFMA tail — wave wv computes 16 nodes x cols [16wv,16wv+16)
    int m16 = lane & 15;      // A: node row / B: output col
    int g = lane >> 4;        // k-group
    f32x4 acc = {0.f, 0.f, 0.f, 0.f};
    const unsigned short* brow = Wc + (wv * 16 + m16) * 320 + g * 8;
#pragma unroll
    for (int kb = 0; kb < 8; ++kb) {   // S part, K=256
        short8 a = *(const short8*)(&Sb[m16 * 264 + kb * 32 + g * 8]);
        short8 b = *(const short8*)(brow + kb * 32);
        acc = __builtin_amdgcn_mfma_f32_16x16x32_bf16(a, b, acc, 0, 0, 0);
    }
    const unsigned short* hrow = hin + (t0 + m16) * HH + g * 8;
#pragma unroll
    for (int kb = 0; kb < 2; ++kb) {   // self part, K=64
        short8 a = *(const short8*)(hrow + kb * 32);
        short8 b = *(const short8*)(brow + 256 + kb * 32);
        acc = __builtin_amdgcn_mfma_f32_16x16x32_bf16(a, b, acc, 0, 0, 0);
    }
    int col = wv * 16 + m16;
    float bias = bself[col];
#pragma unroll
    for (int r = 0; r < 4; ++r) {
        int row = g * 4 + r;
        hout[(t0 + row) * HH + col] = f2bu(fmaxf(acc[r] + bias, 0.f));
    }
}

// stage 1: per-block partial sum & max (h already relu'd)
__global__ void k_reduce(const unsigned short* __restrict__ h, float* __restrict__ psum,
                         float* __restrict__ pmax) {
    __shared__ float ls[256], lm[256];
    int tid = threadIdx.x;
    int j = tid & 63;
    int slot = tid >> 6;
    float s = 0.f, m = -1e30f;
    for (int n = blockIdx.x * 4 + slot; n < NN; n += gridDim.x * 4) {
        float v = bu2f((unsigned)h[n * HH + j]);
        s += v;
        m = fmaxf(m, v);
    }
    ls[tid] = s; lm[tid] = m;
    __syncthreads();
    if (tid < 64) {
        s = ls[tid] + ls[tid + 64] + ls[tid + 128] + ls[tid + 192];
        m = fmaxf(fmaxf(lm[tid], lm[tid + 64]), fmaxf(lm[tid + 128], lm[tid + 192]));
        psum[blockIdx.x * 64 + tid] = s;
        pmax[blockIdx.x * 64 + tid] = m;
    }
}

// stage 2 + readout MLP fused
__global__ void k_finish(const float* __restrict__ psum, const float* __restrict__ pmax,
                         const float* __restrict__ Wr1, const float* __restrict__ br1,
                         const float* __restrict__ Wr2, const float* __restrict__ br2,
                         void* __restrict__ out, const int* __restrict__ flag) {
    __shared__ float ls[256], lm[256];
    __shared__ float g[2 * HH];
    __shared__ float tbuf[HH];
    int tid = threadIdx.x;
    int j = tid & 63;
    int slot = tid >> 6;
    float s = 0.f, m = -1e30f;
    for (int i = slot; i < 256; i += 4) {
        s += psum[i * 64 + j];
        m = fmaxf(m, pmax[i * 64 + j]);
    }
    ls[tid] = s; lm[tid] = m;
    __syncthreads();
    if (tid < 64) {
        s = ls[tid] + ls[tid + 64] + ls[tid + 128] + ls[tid + 192];
        m = fmaxf(fmaxf(lm[tid], lm[tid + 64]), fmaxf(lm[tid + 128], lm[tid + 192]));
        g[tid] = s * (1.0f / NN);
        g[64 + tid] = m;
    }
    __syncthreads();
    if (tid < 64) {
        float acc = br1[tid];
#pragma unroll 8
        for (int k = 0; k < 2 * HH; ++k) acc = fmaf(g[k], Wr1[k * HH + tid], acc);
        tbuf[tid] = fmaxf(acc, 0.f);
    }
    __syncthreads();
    if (tid < EMBD) {
        float acc = br2[tid];
#pragma unroll 8
        for (int k = 0; k < HH; ++k) acc = fmaf(tbuf[k], Wr2[k * EMBD + tid], acc);
        if (*flag) ((float*)out)[tid] = acc;
        else       ((bf16*)out)[tid] = __float2bfloat16(acc);
    }
}

// node_emb via MFMA (same verified fragment layout as k_layer phase 2).
// 16 nodes/block, wave wv covers cols [32wv, 32wv+32). W = hi+lo bf16 split
// -> fp32-equivalent accuracy, 8 MFMAs/wave.
__global__ void __launch_bounds__(256, 8)
k_node_emb2(const unsigned short* __restrict__ h, const unsigned short* __restrict__ WT,
            const float* __restrict__ bnp, void* __restrict__ out,
            const int* __restrict__ flag) {
    int tid = threadIdx.x;
    int lane = tid & 63;
    int wv = tid >> 6;
    int n0 = blockIdx.x * 16;
    int m16 = lane & 15, g = lane >> 4;

    const unsigned short* arow = h + (n0 + m16) * HH + g * 8;
    short8 a0 = *(const short8*)(arow);
    short8 a1 = *(const short8*)(arow + 32);

    int c0 = wv * 32;
    const unsigned short* bp0 = WT + (c0 + m16) * HH + g * 8;          // hi, col tile A
    const unsigned short* bp1 = WT + (c0 + 16 + m16) * HH + g * 8;     // hi, col tile B
    const unsigned short* lp0 = bp0 + EMBD * HH;                       // lo residual
    const unsigned short* lp1 = bp1 + EMBD * HH;

    f32x4 accA = {0.f, 0.f, 0.f, 0.f}, accB = {0.f, 0.f, 0.f, 0.f};
    accA = __builtin_amdgcn_mfma_f32_16x16x32_bf16(a0, *(const short8*)bp0, accA, 0, 0, 0);
    accA = __builtin_amdgcn_mfma_f32_16x16x32_bf16(a1, *(const short8*)(bp0 + 32), accA, 0, 0, 0);
    accA = __builtin_amdgcn_mfma_f32_16x16x32_bf16(a0, *(const short8*)lp0, accA, 0, 0, 0);
    accA = __builtin_amdgcn_mfma_f32_16x16x32_bf16(a1, *(const short8*)(lp0 + 32), accA, 0, 0, 0);
    accB = __builtin_amdgcn_mfma_f32_16x16x32_bf16(a0, *(const short8*)bp1, accB, 0, 0, 0);
    accB = __builtin_amdgcn_mfma_f32_16x16x32_bf16(a1, *(const short8*)(bp1 + 32), accB, 0, 0, 0);
    accB = __builtin_amdgcn_mfma_f32_16x16x32_bf16(a0, *(const short8*)lp1, accB, 0, 0, 0);
    accB = __builtin_amdgcn_mfma_f32_16x16x32_bf16(a1, *(const short8*)(lp1 + 32), accB, 0, 0, 0);

    float biasA = bnp[c0 + m16], biasB = bnp[c0 + 16 + m16];
    if (*flag) {
        float* o = (float*)out + EMBD;
#pragma unroll
        for (int r = 0; r < 4; ++r) {
            long node = n0 + g * 4 + r;
            o[node * EMBD + c0 + m16]      = accA[r] + biasA;
            o[node * EMBD + c0 + 16 + m16] = accB[r] + biasB;
        }
    } else {
        bf16* o = (bf16*)out + EMBD;
#pragma unroll
        for (int r = 0; r < 4; ++r) {
            long node = n0 + g * 4 + r;
            o[node * EMBD + c0 + m16]      = __float2bfloat16(accA[r] + biasA);
            o[node * EMBD + c0 + 16 + m16] = __float2bfloat16(accB[r] + biasB);
        }
    }
}

extern "C" void kernel_launch(void* const* d_in, const int* in_sizes, int n_in,
                              void* d_out, int out_size, void* d_ws, size_t ws_size,
                              hipStream_t stream) {
    const int* eidx  = (const int*)d_in[1];
    const int* etype = (const int*)d_in[2];
    const int* src = eidx;
    const int* tgt = eidx + EE;

    int* flag = (int*)d_ws;
    float* base = (float*)d_ws + 16;

    const int fidx[17] = {0, 3, 4, 5, 6, 7, 8, 9, 10, 11, 12, 13, 14, 15, 16, 17, 18};
    ConvTab tab;
    float* conv[19];
    int cum = 0;
    for (int t = 0; t < 17; ++t) {
        int i = fidx[t];
        tab.in[t] = d_in[i];
        tab.n[t] = in_sizes[i];
        tab.cum[t] = cum;
        conv[i] = base + cum;
        cum += (in_sizes[i] + 15) & ~15;
    }
    tab.cum[17] = cum;

    k_detect<<<1, 64, 0, stream>>>(d_in[3], flag);
    k_convert_all<<<(cum + 255) / 256, 256, 0, stream>>>(tab, base, flag);

    float* p = base + cum;
    float* psum = p;  p += 256 * 64;
    float* pmax = p;  p += 256 * 64;
    float* c16a = p;  p += 64;          // padded 16-row coeff tables (fp32)
    float* c16b = p;  p += 64;
    int* count    = (int*)p;           p += NN;
    int* scanned  = (int*)p;           p += NN;
    int* partials = (int*)p;           p += 512;
    int* rcnt     = (int*)p;           p += NN;   // scatter rank counters
    int* packed   = (int*)p;           p += CAP;
    unsigned short* hbf0 = (unsigned short*)p;          // N*H bf16
    unsigned short* hbf1 = hbf0 + (size_t)NN * HH;
    unsigned short* Wc0  = hbf1 + (size_t)NN * HH;      // 64*320 bf16
    unsigned short* Wc1  = Wc0 + HH * 320;
    unsigned short* WT   = Wc1 + HH * 320;              // 2*128*64 bf16 (hi|lo)

    const float* nf      = conv[0];
    const float* Win     = conv[3];
    const float* bin     = conv[4];
    const float* Wself0  = conv[5];
    const float* bself0  = conv[6];
    const float* bases0  = conv[7];
    const float* coeffs0 = conv[8];
    const float* Wself1  = conv[9];
    const float* bself1  = conv[10];
    const float* bases1  = conv[11];
    const float* coeffs1 = conv[12];
    const float* Wr1     = conv[13];
    const float* br1     = conv[14];
    const float* Wr2     = conv[15];
    const float* br2     = conv[16];
    const float* Wnp     = conv[17];
    const float* bnp     = conv[18];

    const int NHB = (NN * HH) / 256;   // 25000
    const int LYB = NN / 16;           // 6250
    const int EB  = (EE + 255) / 256;  // 3907
    const int IB  = (2 * NN + CAP + 255) / 256;
    const int PB  = (64 + PREP_WCAT + PREP_WT + 255) / 256;

    // edge sort by target, padded with sentinels (shared by both layers)
    k_init<<<IB, 256, 0, stream>>>(count, rcnt, packed);
    k_hist<<<EB, 256, 0, stream>>>(tgt, count);
    k_scan1<<<NP, 256, 0, stream>>>(count, scanned, partials);
    k_scan2<<<1, 512, 0, stream>>>(partials);
    k_scatter<<<EB, 256, 0, stream>>>(src, tgt, etype, scanned, partials, rcnt, packed);

    k_prep<<<PB, 256, 0, stream>>>(coeffs0, coeffs1, c16a, c16b,
                                   bases0, Wself0, bases1, Wself1, Wc0, Wc1, Wnp, WT);
    k_input_proj<<<NHB, 256, 0, stream>>>(nf, Win, bin, hbf0);

    k_layer<<<LYB, 256, 0, stream>>>(hbf0, packed, count, scanned, partials, c16a, Wc0, bself0, hbf1);
    k_layer<<<LYB, 256, 0, stream>>>(hbf1, packed, count, scanned, partials, c16b, Wc1, bself1, hbf0);

    k_reduce<<<256, 256, 0, stream>>>(hbf0, psum, pmax);
    k_finish<<<1, 256, 0, stream>>>(psum, pmax, Wr1, br1, Wr2, br2, d_out, flag);
    k_node_emb2<<<LYB, 256, 0, stream>>>(hbf0, WT, bnp, d_out, flag);
}

// Round 4
// 392.813 us; speedup vs baseline: 1.2277x; 1.2277x over previous
//
#include <hip/hip_runtime.h>
#include <hip/hip_bf16.h>

#define NN 100000
#define EE 1000000
#define FIN 15
#define HH 64
#define EMBD 128
#define RR 13
#define NBASE 4
#define NP 391          // ceil(NN/256) scan blocks
#define CAP 1700128     // EE + 7*NN + slack (padded edge capacity, mult of 16)
#define SENT (15 << 17) // sentinel packed word: src=0, rel=15 (zero coeffs)
#define LYB (NN / 16)   // 6250 layer blocks

typedef __hip_bfloat16 bf16;
typedef __attribute__((ext_vector_type(8))) short short8;   // MFMA A/B frag (8 bf16)
typedef __attribute__((ext_vector_type(4))) float f32x4;    // MFMA C/D frag

__device__ __forceinline__ float b2f(bf16 x) { return __bfloat162float(x); }
__device__ __forceinline__ float bcast(float v, int l) {
    return __uint_as_float(__builtin_amdgcn_readlane(__float_as_uint(v), l));
}
__device__ __forceinline__ int bcasti(int v, int l) {
    return (int)__builtin_amdgcn_readlane((unsigned)v, l);
}
__device__ __forceinline__ unsigned short f2bu(float f) {
    bf16 t = __float2bfloat16(f);
    return *reinterpret_cast<unsigned short*>(&t);
}
__device__ __forceinline__ float bu2f(unsigned u) {
    return __uint_as_float(u << 16);
}

// ---------- dtype auto-detect ----------
__global__ void k_detect(const void* __restrict__ win, int* __restrict__ flag) {
    int tid = threadIdx.x;
    const bf16* p = (const bf16*)win;
    int cnt = 0;
    for (int i = tid; i < FIN * HH; i += 64) {
        float v = b2f(p[i]);
        if (!(fabsf(v) < 0.3f)) cnt++;
    }
#pragma unroll
    for (int off = 32; off > 0; off >>= 1) cnt += __shfl_down(cnt, off, 64);
    if (tid == 0) *flag = (cnt > 40) ? 1 : 0;
}

// ---------- fused convert ----------
struct ConvTab {
    const void* in[17];
    int n[17];
    int cum[18];
};

__global__ void k_convert_all(ConvTab tab, float* __restrict__ base,
                              const int* __restrict__ flag) {
    int g = blockIdx.x * 256 + threadIdx.x;
    if (g >= tab.cum[17]) return;
    int t = 0;
#pragma unroll
    for (int i = 0; i < 17; ++i) if (g >= tab.cum[i + 1]) t = i + 1;
    int local = g - tab.cum[t];
    if (local >= tab.n[t]) return;
    float v;
    if (*flag) v = ((const float*)tab.in[t])[local];
    else       v = b2f(((const bf16*)tab.in[t])[local]);
    base[g] = v;
}

// ---------- edge counting-sort by target (padded to mult-of-8 with sentinels) ----------
__global__ void k_zero(int* __restrict__ a, int n) {
    int i = blockIdx.x * 256 + threadIdx.x;
    if (i < n) a[i] = 0;
}

__global__ void k_fill(int* __restrict__ a, int n, int val) {
    int i = blockIdx.x * 256 + threadIdx.x;
    if (i < n) a[i] = val;
}

__global__ void k_hist(const int* __restrict__ tgt, int* __restrict__ count,
                       int* __restrict__ rank) {
    int e = blockIdx.x * 256 + threadIdx.x;
    if (e >= EE) return;
    rank[e] = atomicAdd(&count[tgt[e]], 1);
}

// exclusive scan over PADDED counts ((c+7)&~7)
__global__ void k_scan1(const int* __restrict__ count, int* __restrict__ scanned,
                        int* __restrict__ partials) {
    __shared__ int buf[256];
    int tid = threadIdx.x;
    int i = blockIdx.x * 256 + tid;
    int v = (i < NN) ? ((count[i] + 7) & ~7) : 0;
    buf[tid] = v;
    __syncthreads();
    for (int off = 1; off < 256; off <<= 1) {
        int t = (tid >= off) ? buf[tid - off] : 0;
        __syncthreads();
        buf[tid] += t;
        __syncthreads();
    }
    if (i < NN) scanned[i] = buf[tid] - v;
    if (tid == 255) partials[blockIdx.x] = buf[255];
}

__global__ void k_scan2(int* __restrict__ partials) {
    __shared__ int buf[512];
    int tid = threadIdx.x;
    int v = (tid < NP) ? partials[tid] : 0;
    buf[tid] = v;
    __syncthreads();
    for (int off = 1; off < 512; off <<= 1) {
        int t = (tid >= off) ? buf[tid - off] : 0;
        __syncthreads();
        buf[tid] += t;
        __syncthreads();
    }
    if (tid < NP) partials[tid] = buf[tid] - v;
}

// packed word: src(17) | etype(4)<<17; sentinel slots stay prefilled
__global__ void k_scatter(const int* __restrict__ src, const int* __restrict__ tgt,
                          const int* __restrict__ et, const int* __restrict__ rank,
                          const int* __restrict__ scanned, const int* __restrict__ partials,
                          int* __restrict__ packed) {
    int e = blockIdx.x * 256 + threadIdx.x;
    if (e >= EE) return;
    int t = tgt[e];
    int pos = scanned[t] + partials[t >> 8] + rank[e];
    packed[pos] = src[e] | (et[e] << 17);
}

// 16-row coeff tables (rows 13..15 = 0 so sentinel edges contribute nothing)
__global__ void k_coef(const float* __restrict__ c0, const float* __restrict__ c1,
                       float* __restrict__ o0, float* __restrict__ o1) {
    int t = threadIdx.x;            // 64 threads
    int r = t >> 2, b = t & 3;
    o0[t] = (r < RR) ? c0[r * NBASE + b] : 0.f;
    o1[t] = (r < RR) ? c1[r * NBASE + b] : 0.f;
}

// WcatT[n][k] bf16, k 0..255: bases[k>>6][k&63][n]; k 256..319: Wself[k-256][n]
__global__ void k_wcat(const float* __restrict__ bases0, const float* __restrict__ Wself0,
                       const float* __restrict__ bases1, const float* __restrict__ Wself1,
                       unsigned short* __restrict__ W0, unsigned short* __restrict__ W1) {
    int idx = blockIdx.x * 256 + threadIdx.x;
    if (idx >= HH * 320) return;
    int n = idx / 320, k = idx - n * 320;
    int b = k >> 6, kk = k & 63;
    float v0 = (b < 4) ? bases0[b * 4096 + kk * 64 + n] : Wself0[kk * 64 + n];
    float v1 = (b < 4) ? bases1[b * 4096 + kk * 64 + n] : Wself1[kk * 64 + n];
    W0[idx] = f2bu(v0);
    W1[idx] = f2bu(v1);
}

// WnpT hi/lo split: WT[0..8191]=hi(col-major [128][64]), WT[8192..]=lo residual.
// hi+lo recovers fp32 weight accuracy through two bf16 MFMAs.
__global__ void k_wt(const float* __restrict__ Wnp, unsigned short* __restrict__ WT) {
    int idx = blockIdx.x * 256 + threadIdx.x;   // 8192
    if (idx >= EMBD * HH) return;
    int c = idx >> 6, k = idx & 63;
    float w = Wnp[k * EMBD + c];
    unsigned short hi = f2bu(w);
    WT[idx] = hi;
    WT[EMBD * HH + idx] = f2bu(w - bu2f(hi));
}

// ---------- pipeline (bf16 node state) ----------

__global__ void k_input_proj(const float* __restrict__ nf, const float* __restrict__ Win,
                             const float* __restrict__ bin, unsigned short* __restrict__ h) {
    __shared__ float w[FIN * HH];
    __shared__ float bb[HH];
    int tid = threadIdx.x;
    for (int i = tid; i < FIN * HH; i += 256) w[i] = Win[i];
    if (tid < HH) bb[tid] = bin[tid];
    __syncthreads();
    int idx = blockIdx.x * 256 + tid;
    if (idx >= NN * HH) return;
    int n = idx >> 6, j = idx & 63;
    float acc = bb[j];
    const float* row = nf + n * FIN;
#pragma unroll
    for (int k = 0; k < FIN; ++k) acc = fmaf(row[k], w[k * HH + j], acc);
    h[idx] = f2bu(acc);
}

// --- k_layer phase-1 inner bodies: edge groups, NO masking (sentinel-padded) ---
// Plain loads (r3 post-mortem: nontemporal hint evicted reused hin lines,
// FETCH +10%, k_layer +9% — reverted).
__device__ __forceinline__ void edge_group16(const unsigned short* __restrict__ hin,
                                             const float* __restrict__ cc,
                                             int lane, int pk, int j, float S[4]) {
    float hv[16];
    int rr[16];
#pragma unroll
    for (int k = 0; k < 16; ++k) {
        int v = bcasti(pk, j + k);          // scalar
        rr[k] = (v >> 17) & 0xF;
        hv[k] = bu2f((unsigned)hin[(v & 0x1FFFF) * HH + lane]);  // 16 gathers in flight
    }
#pragma unroll
    for (int hh = 0; hh < 2; ++hh) {
        float4 cv[8];
#pragma unroll
        for (int k = 0; k < 8; ++k)
            cv[k] = *(const float4*)(cc + rr[hh * 8 + k] * 4);   // uniform -> s_load
#pragma unroll
        for (int k = 0; k < 8; ++k) {
            float hk = hv[hh * 8 + k];
            S[0] = fmaf(cv[k].x, hk, S[0]);
            S[1] = fmaf(cv[k].y, hk, S[1]);
            S[2] = fmaf(cv[k].z, hk, S[2]);
            S[3] = fmaf(cv[k].w, hk, S[3]);
        }
    }
}

__device__ __forceinline__ void edge_group8(const unsigned short* __restrict__ hin,
                                            const float* __restrict__ cc,
                                            int lane, int pk, int j, float S[4]) {
    float hv[8];
    int rr[8];
#pragma unroll
    for (int k = 0; k < 8; ++k) {
        int v = bcasti(pk, j + k);
        rr[k] = (v >> 17) & 0xF;
        hv[k] = bu2f((unsigned)hin[(v & 0x1FFFF) * HH + lane]);
    }
    float4 cv[8];
#pragma unroll
    for (int k = 0; k < 8; ++k) cv[k] = *(const float4*)(cc + rr[k] * 4);
#pragma unroll
    for (int k = 0; k < 8; ++k) {
        float hk = hv[k];
        S[0] = fmaf(cv[k].x, hk, S[0]);
        S[1] = fmaf(cv[k].y, hk, S[1]);
        S[2] = fmaf(cv[k].z, hk, S[2]);
        S[3] = fmaf(cv[k].w, hk, S[3]);
    }
}

__device__ __forceinline__ void gather_node(const unsigned short* __restrict__ hin,
                                            const int* __restrict__ packed,
                                            const float* __restrict__ cc,
                                            int lane, int pk, int s0, int cntp,
                                            float S[4]) {
    int lim = min(64, cntp);                // cntp is a multiple of 8
    int j = 0;
    for (; j + 16 <= lim; j += 16) edge_group16(hin, cc, lane, pk, j, S);
    if (j < lim) edge_group8(hin, cc, lane, pk, j, S);
    for (int base = 64; base < cntp; base += 64) {   // rare overflow (deg > 64)
        int pkx = packed[s0 + base + lane];
        int lim2 = min(64, cntp - base);
        int j2 = 0;
        for (; j2 + 16 <= lim2; j2 += 16) edge_group16(hin, cc, lane, pkx, j2, S);
        if (j2 < lim2) edge_group8(hin, cc, lane, pkx, j2, S);
    }
}

// Fused RGCN layer, 16 nodes/block.
//  phase 1: register gather (sentinel-padded, 16-deep bursts). r2 post-mortem:
//     per-CU miss-throughput bound; depth/occupancy changes measured neutral.
//  phase 2: MFMA tail, out = relu([S|h] @ WcatT^T + bself).
//  TAIL=0 (layer 1): write hout to global.
//  TAIL=1 (layer 2): final h stays in LDS only — fused node_emb MFMA (hi/lo WT)
//     + per-block sum/max partials. Eliminates hout write (12.5 MB) and the
//     k_node_emb2 + k_reduce full re-reads (2 x 12.8 MB + a launch).
template <int TAIL>
__global__ void __launch_bounds__(256, 6)
k_layer(const unsigned short* __restrict__ hin, const int* __restrict__ packed,
        const int* __restrict__ count, const int* __restrict__ scanned,
        const int* __restrict__ partials, const float* __restrict__ cc,
        const unsigned short* __restrict__ Wc, const float* __restrict__ bself,
        unsigned short* __restrict__ hout,
        const unsigned short* __restrict__ WT, const float* __restrict__ bnp,
        void* __restrict__ out, const int* __restrict__ flag,
        float* __restrict__ psum, float* __restrict__ pmax) {
    __shared__ __align__(16) unsigned short Sb[16 * 264];   // row stride 264 (16B-aligned)
    int tid = threadIdx.x;
    int lane = tid & 63;
    int wv = tid >> 6;
    int t0 = blockIdx.x * 16;
    int nb = t0 + wv * 4;

    // metadata for all 4 nodes in 2 int4 loads (+1 scalar: whole block shares t0>>8)
    int4 c4  = *(const int4*)(count + nb);
    int4 sc4 = *(const int4*)(scanned + nb);
    int pb = partials[t0 >> 8];
    int s00 = sc4.x + pb, s01 = sc4.y + pb, s02 = sc4.z + pb, s03 = sc4.w + pb;
    int cp0 = (c4.x + 7) & ~7, cp1 = (c4.y + 7) & ~7;
    int cp2 = (c4.z + 7) & ~7, cp3 = (c4.w + 7) & ~7;

    // prefetch packed words for all 4 nodes (4 loads in flight before any consume)
    int pk0 = packed[s00 + lane];
    int pk1 = packed[s01 + lane];
    int pk2 = packed[s02 + lane];
    int pk3 = packed[s03 + lane];

    float S0[4] = {0, 0, 0, 0}, S1[4] = {0, 0, 0, 0};
    float S2[4] = {0, 0, 0, 0}, S3[4] = {0, 0, 0, 0};
    gather_node(hin, packed, cc, lane, pk0, s00, cp0, S0);
    gather_node(hin, packed, cc, lane, pk1, s01, cp1, S1);
    gather_node(hin, packed, cc, lane, pk2, s02, cp2, S2);
    gather_node(hin, packed, cc, lane, pk3, s03, cp3, S3);

    // write S to LDS bf16: row = local node, k = b*64+lane  (stride-1 across lanes)
#pragma unroll
    for (int b = 0; b < NBASE; ++b) {
        Sb[(wv * 4 + 0) * 264 + b * 64 + lane] = f2bu(S0[b]);
        Sb[(wv * 4 + 1) * 264 + b * 64 + lane] = f2bu(S1[b]);
        Sb[(wv * 4 + 2) * 264 + b * 64 + lane] = f2bu(S2[b]);
        Sb[(wv * 4 + 3) * 264 + b * 64 + lane] = f2bu(S3[b]);
    }
    __syncthreads();

    // phase 2: MFMA tail — wave wv computes 16 nodes x cols [16wv,16wv+16)
    int m16 = lane & 15;      // A: node row / B: output col
    int g = lane >> 4;        // k-group
    f32x4 acc = {0.f, 0.f, 0.f, 0.f};
    const unsigned short* brow = Wc + (wv * 16 + m16) * 320 + g * 8;
#pragma unroll
    for (int kb = 0; kb < 8; ++kb) {   // S part, K=256
        short8 a = *(const short8*)(&Sb[m16 * 264 + kb * 32 + g * 8]);
        short8 b = *(const short8*)(brow + kb * 32);
        acc = __builtin_amdgcn_mfma_f32_16x16x32_bf16(a, b, acc, 0, 0, 0);
    }
    const unsigned short* hrow = hin + (t0 + m16) * HH + g * 8;
#pragma unroll
    for (int kb = 0; kb < 2; ++kb) {   // self part, K=64
        short8 a = *(const short8*)(hrow + kb * 32);
        short8 b = *(const short8*)(brow + 256 + kb * 32);
        acc = __builtin_amdgcn_mfma_f32_16x16x32_bf16(a, b, acc, 0, 0, 0);
    }
    int col = wv * 16 + m16;
    float bias = bself[col];

    if (TAIL == 0) {
#pragma unroll
        for (int r = 0; r < 4; ++r) {
            int row = g * 4 + r;
            hout[(t0 + row) * HH + col] = f2bu(fmaxf(acc[r] + bias, 0.f));
        }
        return;
    }

    // ---- TAIL==1 epilogue: h stays in LDS ----
    __syncthreads();        // all waves done reading Sb (S-part MFMA)
#pragma unroll
    for (int r = 0; r < 4; ++r)
        Sb[(g * 4 + r) * 264 + col] = f2bu(fmaxf(acc[r] + bias, 0.f));
    __syncthreads();

    // node_emb: wave wv covers cols [32wv, 32wv+32), A-frags from LDS
    const unsigned short* ar = &Sb[m16 * 264 + g * 8];
    short8 a0 = *(const short8*)(ar);
    short8 a1 = *(const short8*)(ar + 32);
    int c0 = wv * 32;
    const unsigned short* bp0 = WT + (c0 + m16) * HH + g * 8;          // hi, col tile A
    const unsigned short* bp1 = WT + (c0 + 16 + m16) * HH + g * 8;     // hi, col tile B
    const unsigned short* lp0 = bp0 + EMBD * HH;                       // lo residual
    const unsigned short* lp1 = bp1 + EMBD * HH;

    f32x4 eA = {0.f, 0.f, 0.f, 0.f}, eB = {0.f, 0.f, 0.f, 0.f};
    eA = __builtin_amdgcn_mfma_f32_16x16x32_bf16(a0, *(const short8*)bp0, eA, 0, 0, 0);
    eA = __builtin_amdgcn_mfma_f32_16x16x32_bf16(a1, *(const short8*)(bp0 + 32), eA, 0, 0, 0);
    eA = __builtin_amdgcn_mfma_f32_16x16x32_bf16(a0, *(const short8*)lp0, eA, 0, 0, 0);
    eA = __builtin_amdgcn_mfma_f32_16x16x32_bf16(a1, *(const short8*)(lp0 + 32), eA, 0, 0, 0);
    eB = __builtin_amdgcn_mfma_f32_16x16x32_bf16(a0, *(const short8*)bp1, eB, 0, 0, 0);
    eB = __builtin_amdgcn_mfma_f32_16x16x32_bf16(a1, *(const short8*)(bp1 + 32), eB, 0, 0, 0);
    eB = __builtin_amdgcn_mfma_f32_16x16x32_bf16(a0, *(const short8*)lp1, eB, 0, 0, 0);
    eB = __builtin_amdgcn_mfma_f32_16x16x32_bf16(a1, *(const short8*)(lp1 + 32), eB, 0, 0, 0);

    float biasA = bnp[c0 + m16], biasB = bnp[c0 + 16 + m16];
    if (*flag) {
        float* o = (float*)out + EMBD;
#pragma unroll
        for (int r = 0; r < 4; ++r) {
            long node = t0 + g * 4 + r;
            o[node * EMBD + c0 + m16]      = eA[r] + biasA;
            o[node * EMBD + c0 + 16 + m16] = eB[r] + biasB;
        }
    } else {
        bf16* o = (bf16*)out + EMBD;
#pragma unroll
        for (int r = 0; r < 4; ++r) {
            long node = t0 + g * 4 + r;
            o[node * EMBD + c0 + m16]      = __float2bfloat16(eA[r] + biasA);
            o[node * EMBD + c0 + 16 + m16] = __float2bfloat16(eB[r] + biasB);
        }
    }

    // per-block sum/max partials over the 16 LDS rows (wave 0; 2-way bank alias = free)
    if (wv == 0) {
        float s = 0.f, m = -1e30f;
#pragma unroll
        for (int r16 = 0; r16 < 16; ++r16) {
            float v = bu2f((unsigned)Sb[r16 * 264 + lane]);
            s += v;
            m = fmaxf(m, v);
        }
        psum[blockIdx.x * 64 + lane] = s;
        pmax[blockIdx.x * 64 + lane] = m;
    }
}

// reduce 6250 block-partials -> 256 (layout matches k_finish's expectation)
__global__ void k_reduce2(const float* __restrict__ psum, const float* __restrict__ pmax,
                          float* __restrict__ psum2, float* __restrict__ pmax2) {
    __shared__ float ls[256], lm[256];
    int tid = threadIdx.x;
    int j = tid & 63;
    int slot = tid >> 6;
    float s = 0.f, m = -1e30f;
    for (int n = blockIdx.x * 4 + slot; n < LYB; n += 256 * 4) {
        s += psum[n * 64 + j];
        m = fmaxf(m, pmax[n * 64 + j]);
    }
    ls[tid] = s; lm[tid] = m;
    __syncthreads();
    if (tid < 64) {
        s = ls[tid] + ls[tid + 64] + ls[tid + 128] + ls[tid + 192];
        m = fmaxf(fmaxf(lm[tid], lm[tid + 64]), fmaxf(lm[tid + 128], lm[tid + 192]));
        psum2[blockIdx.x * 64 + tid] = s;
        pmax2[blockIdx.x * 64 + tid] = m;
    }
}

// stage 2 + readout MLP fused
__global__ void k_finish(const float* __restrict__ psum, const float* __restrict__ pmax,
                         const float* __restrict__ Wr1, const float* __restrict__ br1,
                         const float* __restrict__ Wr2, const float* __restrict__ br2,
                         void* __restrict__ out, const int* __restrict__ flag) {
    __shared__ float ls[256], lm[256];
    __shared__ float g[2 * HH];
    __shared__ float tbuf[HH];
    int tid = threadIdx.x;
    int j = tid & 63;
    int slot = tid >> 6;
    float s = 0.f, m = -1e30f;
    for (int i = slot; i < 256; i += 4) {
        s += psum[i * 64 + j];
        m = fmaxf(m, pmax[i * 64 + j]);
    }
    ls[tid] = s; lm[tid] = m;
    __syncthreads();
    if (tid < 64) {
        s = ls[tid] + ls[tid + 64] + ls[tid + 128] + ls[tid + 192];
        m = fmaxf(fmaxf(lm[tid], lm[tid + 64]), fmaxf(lm[tid + 128], lm[tid + 192]));
        g[tid] = s * (1.0f / NN);
        g[64 + tid] = m;
    }
    __syncthreads();
    if (tid < 64) {
        float acc = br1[tid];
#pragma unroll 8
        for (int k = 0; k < 2 * HH; ++k) acc = fmaf(g[k], Wr1[k * HH + tid], acc);
        tbuf[tid] = fmaxf(acc, 0.f);
    }
    __syncthreads();
    if (tid < EMBD) {
        float acc = br2[tid];
#pragma unroll 8
        for (int k = 0; k < HH; ++k) acc = fmaf(tbuf[k], Wr2[k * EMBD + tid], acc);
        if (*flag) ((float*)out)[tid] = acc;
        else       ((bf16*)out)[tid] = __float2bfloat16(acc);
    }
}

extern "C" void kernel_launch(void* const* d_in, const int* in_sizes, int n_in,
                              void* d_out, int out_size, void* d_ws, size_t ws_size,
                              hipStream_t stream) {
    const int* eidx  = (const int*)d_in[1];
    const int* etype = (const int*)d_in[2];
    const int* src = eidx;
    const int* tgt = eidx + EE;

    int* flag = (int*)d_ws;
    float* base = (float*)d_ws + 16;

    const int fidx[17] = {0, 3, 4, 5, 6, 7, 8, 9, 10, 11, 12, 13, 14, 15, 16, 17, 18};
    ConvTab tab;
    float* conv[19];
    int cum = 0;
    for (int t = 0; t < 17; ++t) {
        int i = fidx[t];
        tab.in[t] = d_in[i];
        tab.n[t] = in_sizes[i];
        tab.cum[t] = cum;
        conv[i] = base + cum;
        cum += (in_sizes[i] + 15) & ~15;
    }
    tab.cum[17] = cum;

    k_detect<<<1, 64, 0, stream>>>(d_in[3], flag);
    k_convert_all<<<(cum + 255) / 256, 256, 0, stream>>>(tab, base, flag);

    float* p = base + cum;
    float* psum  = p;  p += LYB * 64;   // per-block partials (layer-2 epilogue)
    float* pmax  = p;  p += LYB * 64;
    float* psum2 = p;  p += 256 * 64;
    float* pmax2 = p;  p += 256 * 64;
    float* c16a = p;  p += 64;          // padded 16-row coeff tables (fp32)
    float* c16b = p;  p += 64;
    int* count    = (int*)p;           p += NN;
    int* scanned  = (int*)p;           p += NN;
    int* partials = (int*)p;           p += 512;
    int* rank     = (int*)p;           p += EE;
    int* packed   = (int*)p;           p += CAP;
    unsigned short* hbf0 = (unsigned short*)p;          // N*H bf16
    unsigned short* hbf1 = hbf0 + (size_t)NN * HH;
    unsigned short* Wc0  = hbf1 + (size_t)NN * HH;      // 64*320 bf16
    unsigned short* Wc1  = Wc0 + HH * 320;
    unsigned short* WT   = Wc1 + HH * 320;              // 2*128*64 bf16 (hi|lo)

    const float* nf      = conv[0];
    const float* Win     = conv[3];
    const float* bin     = conv[4];
    const float* Wself0  = conv[5];
    const float* bself0  = conv[6];
    const float* bases0  = conv[7];
    const float* coeffs0 = conv[8];
    const float* Wself1  = conv[9];
    const float* bself1  = conv[10];
    const float* bases1  = conv[11];
    const float* coeffs1 = conv[12];
    const float* Wr1     = conv[13];
    const float* br1     = conv[14];
    const float* Wr2     = conv[15];
    const float* br2     = conv[16];
    const float* Wnp     = conv[17];
    const float* bnp     = conv[18];

    const int NHB = (NN * HH) / 256;   // 25000
    const int EB  = (EE + 255) / 256;  // 3907

    // edge sort by target, padded with sentinels (shared by both layers)
    k_zero<<<(NN + 255) / 256, 256, 0, stream>>>(count, NN);
    k_fill<<<(CAP + 255) / 256, 256, 0, stream>>>(packed, CAP, SENT);
    k_hist<<<EB, 256, 0, stream>>>(tgt, count, rank);
    k_scan1<<<NP, 256, 0, stream>>>(count, scanned, partials);
    k_scan2<<<1, 512, 0, stream>>>(partials);
    k_scatter<<<EB, 256, 0, stream>>>(src, tgt, etype, rank, scanned, partials, packed);

    k_coef<<<1, 64, 0, stream>>>(coeffs0, coeffs1, c16a, c16b);
    k_wcat<<<(HH * 320 + 255) / 256, 256, 0, stream>>>(bases0, Wself0, bases1, Wself1, Wc0, Wc1);
    k_wt<<<(EMBD * HH + 255) / 256, 256, 0, stream>>>(Wnp, WT);
    k_input_proj<<<NHB, 256, 0, stream>>>(nf, Win, bin, hbf0);

    k_layer<0><<<LYB, 256, 0, stream>>>(hbf0, packed, count, scanned, partials, c16a, Wc0, bself0,
                                        hbf1, nullptr, nullptr, nullptr, nullptr, nullptr, nullptr);
    k_layer<1><<<LYB, 256, 0, stream>>>(hbf1, packed, count, scanned, partials, c16b, Wc1, bself1,
                                        hbf0, WT, bnp, d_out, flag, psum, pmax);

    k_reduce2<<<256, 256, 0, stream>>>(psum, pmax, psum2, pmax2);
    k_finish<<<1, 256, 0, stream>>>(psum2, pmax2, Wr1, br1, Wr2, br2, d_out, flag);
}